// Round 10
// baseline (63.256 us; speedup 1.0000x reference)
//
#include <hip/hip_runtime.h>
#include <math.h>

#define NR 50      // rho grid points per dim
#define NP 200     // phi grid points per dim
#define NM 400     // mirrored width (2*NP)
#define SCADD 1e-12
#define BW 8       // numerical bandwidth of K = band of its Cholesky factor
#define LST 18     // L row stride: 0..7 margin zeros, 8..15 band t=8..1, 16 diag, 17 pad
#define DG 16      // diagonal slot
#define LROWS (NR + BW)
#define TST 51     // Tlds row stride

// ws layout (in doubles)
#define OFF_CNT  30000    // penalty completion counter (int, memset to 0 per call)
#define OFF_PART 240000   // per-block penalty partials
#define NTA 13            // a-tiles (ceil 200/16)
#define NTB2 25           // b-tiles (400/16)
#define NBLK_PEN (NTA*NTB2)   // 325

// dynamic-LDS offsets (in doubles)
#define S_LF    0                 // Lf   [LROWS*LST] = 1044
#define S_ID    1044              // iD   [50]
#define S_TLDS  1100              // Tlds [50*51] = 2550
#define S_MTS   3650              // Mts  [50*50]  (Mts[ix*50+iy] = M[iy][ix])
#define S_ATS   6150              // Ats  [20*51]
#define S_BTS   7170              // Bts  [20*51]
#define S_T2S   8190              // T2s  [50*21]
#define S_ETILE 9240              // Etile[20*21]
#define S_SDATA 9660              // sdata[256]
#define S_TOTAL 9916              // 79,328 bytes

// One kernel: every block redundantly runs the 1-wave banded solve (latency-
// bound, runs in parallel across blocks -> same wall time as one solve, zero
// cross-block sync), then computes its own 16x16 penalty tile.
__global__ __launch_bounds__(256) void fused_kernel(
        const float* __restrict__ params,
        const float* __restrict__ x_rho,
        const float* __restrict__ y_rho,
        const float* __restrict__ x_phi,
        const float* __restrict__ y_phi,
        double* __restrict__ ws,
        float* __restrict__ out) {
    extern __shared__ double sm[];
    double* Lf    = sm + S_LF;
    double* iD    = sm + S_ID;
    double* Tlds  = sm + S_TLDS;
    double* Mts   = sm + S_MTS;
    double* Ats   = sm + S_ATS;
    double* Bts   = sm + S_BTS;
    double* T2s   = sm + S_T2S;
    double* Etile = sm + S_ETILE;
    double* sdata = sm + S_SDATA;
    __shared__ bool last;

    const int tid  = threadIdx.x;
    const int wave = tid >> 6;
    const int lane = tid & 63;
    const int ba = blockIdx.x / NTB2, bbt = blockIdx.x % NTB2;
    const int a0 = ba*16, b0 = bbt*16;

    const double Lr = (double)y_rho[NR-1] - (double)y_rho[0];
    const double sigma = 0.8 * Lr / (double)(NR - 1);
    const double inv2s2 = 1.0 / (2.0 * sigma * sigma);
    const double g = ((double)x_phi[NP-1] - (double)x_phi[0]) / (double)(NP - 1);
    const double pi_d = M_PI / 1.1;

    if (wave == 0) {
        // ---- wave 0: band build + barrier-free banded Cholesky ----
        for (int i = lane; i < LROWS*LST; i += 64) Lf[i] = 0.0;
        for (int idx = lane; idx < NR*(BW+1); idx += 64) {
            int i = idx / (BW+1), t = idx % (BW+1);
            int k = i - t;
            if (k >= 0) {
                double d = (double)y_rho[i] - (double)y_rho[k];
                Lf[i*LST + DG - t] = exp(-d*d*inv2s2);
            }
        }
        for (int j = 0; j < NR; ++j) {
            const int i = j + lane;
            double s = 0.0;
            if (lane <= BW && i < NR) {
                s = Lf[i*LST + DG - lane];
                #pragma unroll
                for (int t = 1; t <= BW; ++t)       // margins absorb oob as 0
                    s -= Lf[i*LST + DG - lane - t] * Lf[j*LST + DG - t];
            }
            double dg = sqrt(__shfl(s, 0, 64));     // lane 0 holds diag dot
            double invd = 1.0 / dg;
            if (lane <= BW && i < NR) {
                Lf[i*LST + DG - lane] = (lane == 0) ? dg : s * invd;
                if (lane == 0) iD[j] = invd;
            }
        }
    } else {
        // ---- waves 1-3 (overlapped with Cholesky): params + tile tables ----
        for (int idx = tid - 64; idx < NR*NR; idx += 192) {
            int i = idx / NR, c = idx % NR;
            Tlds[i*TST + c] = (double)params[idx];
        }
        for (int e = tid - 64; e < 20*NR; e += 192) {
            int r = e / NR, iy = e % NR;
            int aab = a0 - 2 + r; aab = aab < 0 ? 0 : (aab > NP-1 ? NP-1 : aab);
            double da = (double)y_phi[aab] - (double)y_rho[iy];
            Ats[r*51 + iy] = exp(-da*da*inv2s2);
            int mb = b0 - 2 + r;  mb = mb < 0 ? 0 : (mb > NM-1 ? NM-1 : mb);
            int bb = (mb < NP) ? mb : (NM-1 - mb);     // mirror to base col
            double db = (double)x_phi[bb] - (double)x_rho[iy];
            Bts[r*51 + iy] = exp(-db*db*inv2s2);
        }
    }
    __syncthreads();

    // ---- wave 0, lanes<50: sliding-window triangular solves (R8-proven) ----
    if (tid < NR) {
        const int c = tid;
        double w1=0,w2=0,w3=0,w4=0,w5=0,w6=0,w7=0,w8=0;
        #pragma unroll 2
        for (int i = 0; i < NR; ++i) {              // phase1 forward L y = p
            const double* Lr_ = Lf + i*LST + DG;
            double s = Tlds[i*TST + c];
            s -= Lr_[-8]*w8; s -= Lr_[-7]*w7; s -= Lr_[-6]*w6; s -= Lr_[-5]*w5;
            s -= Lr_[-4]*w4; s -= Lr_[-3]*w3; s -= Lr_[-2]*w2; s -= Lr_[-1]*w1;
            s *= iD[i];
            Tlds[i*TST + c] = s;
            w8=w7; w7=w6; w6=w5; w5=w4; w4=w3; w3=w2; w2=w1; w1=s;
        }
        double v1=0,v2=0,v3=0,v4=0,v5=0,v6=0,v7=0,v8=0;
        #pragma unroll 2
        for (int i = NR-1; i >= 0; --i) {           // phase1 backward L^T x = y
            double s = Tlds[i*TST + c];
            s -= Lf[(i+8)*LST + DG-8]*v8; s -= Lf[(i+7)*LST + DG-7]*v7;
            s -= Lf[(i+6)*LST + DG-6]*v6; s -= Lf[(i+5)*LST + DG-5]*v5;
            s -= Lf[(i+4)*LST + DG-4]*v4; s -= Lf[(i+3)*LST + DG-3]*v3;
            s -= Lf[(i+2)*LST + DG-2]*v2; s -= Lf[(i+1)*LST + DG-1]*v1;
            s *= iD[i];
            Tlds[i*TST + c] = s;
            v8=v7; v7=v6; v6=v5; v5=v4; v4=v3; v3=v2; v2=v1; v1=s;
        }
        // phase2 on own row r=c (same wave -> in-order LDS, no barrier)
        const int r = c;
        double u1=0,u2=0,u3=0,u4=0,u5=0,u6=0,u7=0,u8=0;
        #pragma unroll 2
        for (int i = 0; i < NR; ++i) {              // forward on T row r
            const double* Lr_ = Lf + i*LST + DG;
            double s = Tlds[r*TST + i];
            s -= Lr_[-8]*u8; s -= Lr_[-7]*u7; s -= Lr_[-6]*u6; s -= Lr_[-5]*u5;
            s -= Lr_[-4]*u4; s -= Lr_[-3]*u3; s -= Lr_[-2]*u2; s -= Lr_[-1]*u1;
            s *= iD[i];
            Tlds[r*TST + i] = s;
            u8=u7; u7=u6; u6=u5; u5=u4; u4=u3; u3=u2; u2=u1; u1=s;
        }
        double t1=0,t2=0,t3=0,t4=0,t5=0,t6=0,t7=0,t8=0;
        #pragma unroll 2
        for (int i = NR-1; i >= 0; --i) {           // backward; z_i -> Mts[i][r]
            double s = Tlds[r*TST + i];
            s -= Lf[(i+8)*LST + DG-8]*t8; s -= Lf[(i+7)*LST + DG-7]*t7;
            s -= Lf[(i+6)*LST + DG-6]*t6; s -= Lf[(i+5)*LST + DG-5]*t5;
            s -= Lf[(i+4)*LST + DG-4]*t4; s -= Lf[(i+3)*LST + DG-3]*t3;
            s -= Lf[(i+2)*LST + DG-2]*t2; s -= Lf[(i+1)*LST + DG-1]*t1;
            s *= iD[i];
            Mts[i*NR + r] = s;                      // M^T in LDS
            t8=t7; t7=t6; t6=t5; t5=t4; t4=t3; t3=t2; t2=t1; t1=s;
        }
    }
    __syncthreads();

    // ---- T2s[iy][kc] = sum_ix M[iy][ix] * Bt_kc[ix] ----
    for (int e = tid; e < 20*NR; e += 256) {
        int kc = e / NR, iy = e % NR;
        double s = 0.0;
        #pragma unroll 10
        for (int ix = 0; ix < NR; ++ix) s += Mts[ix*NR + iy] * Bts[kc*51 + ix];
        T2s[iy*21 + kc] = s;
    }
    __syncthreads();

    // ---- Etile[r][kc] = eps at (a0-2+r, mirrored(b0-2+kc)) ----
    for (int e = tid; e < 20*20; e += 256) {
        int r = e / 20, kc = e % 20;
        double s = 0.0;
        #pragma unroll 10
        for (int iy = 0; iy < NR; ++iy) s += Ats[r*51 + iy] * T2s[iy*21 + kc];
        Etile[r*21 + kc] = 0.5 * (tanh(0.1 * s) + 1.0);
    }
    __syncthreads();

    // ---- stencil derivatives + curvature penalty ----
    auto EXf = [&](int r, int k) -> double {
        int aab = a0 - 2 + r;
        if (aab == 0)      return (Etile[(r+1)*21+k] - Etile[r*21+k])     / g + SCADD;
        if (aab == NP-1)   return (Etile[r*21+k]     - Etile[(r-1)*21+k]) / g + SCADD;
        return (Etile[(r+1)*21+k] - Etile[(r-1)*21+k]) / (2.0*g) + SCADD;
    };
    auto EYf = [&](int r, int k) -> double {
        int bab = b0 - 2 + k;
        if (bab == 0)      return (Etile[r*21+k+1] - Etile[r*21+k])   / g + SCADD;
        if (bab == NM-1)   return (Etile[r*21+k]   - Etile[r*21+k-1]) / g + SCADD;
        return (Etile[r*21+k+1] - Etile[r*21+k-1]) / (2.0*g) + SCADD;
    };

    double local = 0.0;
    {
        const int aa = tid / 16, bb_ = tid % 16;
        const int a = a0 + aa, b = b0 + bb_;
        if (a < NP) {                               // b < NM always
            const int ar = aa + 2, kc = bb_ + 2;
            const double exv = EXf(ar, kc);
            const double eyv = EYf(ar, kc);
            double exx, exy, eyy;
            if (a == 0)         exx = (EXf(ar+1,kc) - EXf(ar,kc))   / g;
            else if (a == NP-1) exx = (EXf(ar,kc)   - EXf(ar-1,kc)) / g;
            else                exx = (EXf(ar+1,kc) - EXf(ar-1,kc)) / (2.0*g);
            if (b == 0)         exy = (EXf(ar,kc+1) - EXf(ar,kc))   / g;
            else if (b == NM-1) exy = (EXf(ar,kc)   - EXf(ar,kc-1)) / g;
            else                exy = (EXf(ar,kc+1) - EXf(ar,kc-1)) / (2.0*g);
            if (b == 0)         eyy = (EYf(ar,kc+1) - EYf(ar,kc))   / g;
            else if (b == NM-1) eyy = (EYf(ar,kc)   - EYf(ar,kc-1)) / g;
            else                eyy = (EYf(ar,kc+1) - EYf(ar,kc-1)) / (2.0*g);

            double epsv = sqrt(exv*exv + eyv*eyv);
            const double epsv_min = 1e-32 / 6.0;
            if (epsv < epsv_min) epsv = epsv_min;
            const double kk = (exv*exv*eyy - 2.0*exv*eyv*exy + eyv*eyv*exx)
                              / (epsv*epsv*epsv);
            const double cc = fabs(kk * atan(epsv / Etile[ar*21+kc])) - pi_d;
            double v = fmax(cc, 0.0) * g * g;
            if (!isnan(v)) local = v;
        }
    }
    sdata[tid] = local;
    __syncthreads();
    for (int s = 128; s > 0; s >>= 1) {
        if (tid < s) sdata[tid] += sdata[tid + s];
        __syncthreads();
    }
    double* part = ws + OFF_PART;
    if (tid == 0) {
        part[blockIdx.x] = sdata[0];
        __threadfence();
        int old = atomicAdd((int*)(ws + OFF_CNT), 1);   // device-scope
        last = (old == NBLK_PEN - 1);
    }
    __syncthreads();
    if (last) {                                         // block-uniform branch
        __threadfence();
        double s = 0.0;
        for (int i = tid; i < NBLK_PEN; i += 256) s += part[i];  // fixed order
        sdata[tid] = s;
        __syncthreads();
        for (int w = 128; w > 0; w >>= 1) {
            if (tid < w) sdata[tid] += sdata[tid + w];
            __syncthreads();
        }
        if (tid == 0) out[0] = (float)sdata[0];
    }
}

extern "C" void kernel_launch(void* const* d_in, const int* in_sizes, int n_in,
                              void* d_out, int out_size, void* d_ws, size_t ws_size,
                              hipStream_t stream) {
    const float* params = (const float*)d_in[0];
    const float* x_rho  = (const float*)d_in[1];
    const float* y_rho  = (const float*)d_in[2];
    const float* x_phi  = (const float*)d_in[3];
    const float* y_phi  = (const float*)d_in[4];
    double* ws = (double*)d_ws;
    float* out = (float*)d_out;

    // arm the completion counter (graph-capturable async memset)
    hipMemsetAsync((char*)d_ws + OFF_CNT*sizeof(double), 0, sizeof(int), stream);
    fused_kernel<<<NBLK_PEN, 256, S_TOTAL*sizeof(double), stream>>>(
        params, x_rho, y_rho, x_phi, y_phi, ws, out);
}

// Round 11
// 47.280 us; speedup vs baseline: 1.3379x; 1.3379x over previous
//
#include <hip/hip_runtime.h>
#include <math.h>

#define NR 50      // rho grid points per dim
#define NP 200     // phi grid points per dim
#define NM 400     // mirrored width (2*NP)
#define SCADDF 1e-12f
#define BW 8       // band of K / its Cholesky factor
#define LST 18     // L row stride: 0..7 margin, 8..15 band t=8..1, 16 diag, 17 pad
#define DG 16
#define LROWS (NR + BW)

// ws layout (in doubles) — counter + partials only
#define OFF_CNT  30000
#define OFF_PART 240000
#define NTA 13
#define NTB2 25
#define NBLK_PEN (NTA*NTB2)   // 325

// Single fused kernel, fp32 compute / fp64 accumulation.
// Every block redundantly factorizes K (fp32 banded Cholesky, 1 wave,
// barrier-free) and solves ONLY its own 40 tile RHS: c_a = W at_a (20),
// d_b = W bt_b (20), W = K^{-1}. Then phi[a,b] = c_a^T P d_b via two small
// LDS GEMMs, eps = 0.5(tanhf(.1 phi)+1), stencil curvature, fp64 reduce.
__global__ __launch_bounds__(256) void fused_kernel(
        const float* __restrict__ params,
        const float* __restrict__ x_rho,
        const float* __restrict__ y_rho,
        const float* __restrict__ x_phi,
        const float* __restrict__ y_phi,
        double* __restrict__ ws,
        float* __restrict__ out) {
    __shared__ float Lb[LROWS * LST];   // K band -> L (margins zero)
    __shared__ float iDf[NR];           // 1/diag
    __shared__ float Pf[NR * 51];       // params staged
    __shared__ float ATf[20 * 51];      // at rows (a-halo, clamped)
    __shared__ float BTf[20 * 51];      // bt rows (b-halo, mirrored+clamped)
    __shared__ float CDf[40 * 51];      // solved c (0..19) / d (20..39)
    __shared__ float Ef[20 * 51];       // E_a[k] = c_a^T P
    __shared__ float ETf[20 * 21];      // eps tile with halo
    __shared__ double sdata[256];
    __shared__ bool last;

    const int tid  = threadIdx.x;
    const int wave = tid >> 6;
    const int lane = tid & 63;
    const int ba = blockIdx.x / NTB2, bbt = blockIdx.x % NTB2;
    const int a0 = ba*16, b0 = bbt*16;

    const float Lr = y_rho[NR-1] - y_rho[0];
    const float sigma = 0.8f * Lr / (float)(NR - 1);
    const float inv2s2 = 1.0f / (2.0f * sigma * sigma);
    const float g = (x_phi[NP-1] - x_phi[0]) / (float)(NP - 1);
    const float pi_d = (float)(M_PI / 1.1);

    if (wave == 0) {
        // ---- wave 0: zero+build band, barrier-free banded Cholesky ----
        for (int i = lane; i < LROWS*LST; i += 64) Lb[i] = 0.0f;
        for (int idx = lane; idx < NR*(BW+1); idx += 64) {
            int i = idx / (BW+1), t = idx % (BW+1);
            int k = i - t;
            if (k >= 0) {
                float d = y_rho[i] - y_rho[k];
                Lb[i*LST + DG - t] = expf(-d*d*inv2s2);
            }
        }
        for (int j = 0; j < NR; ++j) {
            const int i = j + lane;
            float s = 0.0f;
            if (lane <= BW && i < NR) {
                s = Lb[i*LST + DG - lane];
                #pragma unroll
                for (int t = 1; t <= BW; ++t)       // margins absorb oob as 0
                    s -= Lb[i*LST + DG - lane - t] * Lb[j*LST + DG - t];
            }
            float dg = sqrtf(__shfl(s, 0, 64));     // lane 0 holds diag dot
            float invd = 1.0f / dg;
            if (lane <= BW && i < NR) {
                Lb[i*LST + DG - lane] = (lane == 0) ? dg : s * invd;
                if (lane == 0) iDf[j] = invd;
            }
        }
    } else {
        // ---- waves 1-3 (overlap chol): stage P + build tile tables ----
        for (int idx = tid - 64; idx < NR*NR; idx += 192)
            Pf[(idx/NR)*51 + (idx%NR)] = params[idx];
        for (int e = tid - 64; e < 20*NR; e += 192) {
            int r = e / NR, iy = e % NR;
            int aab = a0 - 2 + r; aab = aab < 0 ? 0 : (aab > NP-1 ? NP-1 : aab);
            float da = y_phi[aab] - y_rho[iy];
            ATf[r*51 + iy] = expf(-da*da*inv2s2);
            int mb = b0 - 2 + r;  mb = mb < 0 ? 0 : (mb > NM-1 ? NM-1 : mb);
            int bb = (mb < NP) ? mb : (NM-1 - mb);   // mirror to base col
            float db = x_phi[bb] - x_rho[iy];
            BTf[r*51 + iy] = expf(-db*db*inv2s2);
        }
    }
    __syncthreads();

    // ---- lanes 0..39: solve K v = rhs (40 RHS), sliding 8-reg window ----
    if (tid < 40) {
        const float* rhs = (tid < 20) ? (ATf + tid*51) : (BTf + (tid-20)*51);
        float* cd = CDf + tid*51;
        float w1=0,w2=0,w3=0,w4=0,w5=0,w6=0,w7=0,w8=0;
        #pragma unroll 2
        for (int i = 0; i < NR; ++i) {              // forward L y = rhs
            const float* Lr_ = Lb + i*LST + DG;
            float s = rhs[i];
            s -= Lr_[-8]*w8; s -= Lr_[-7]*w7; s -= Lr_[-6]*w6; s -= Lr_[-5]*w5;
            s -= Lr_[-4]*w4; s -= Lr_[-3]*w3; s -= Lr_[-2]*w2; s -= Lr_[-1]*w1;
            s *= iDf[i];
            cd[i] = s;
            w8=w7; w7=w6; w6=w5; w5=w4; w4=w3; w3=w2; w2=w1; w1=s;
        }
        float v1=0,v2=0,v3=0,v4=0,v5=0,v6=0,v7=0,v8=0;
        #pragma unroll 2
        for (int i = NR-1; i >= 0; --i) {           // backward L^T x = y
            float s = cd[i];
            s -= Lb[(i+8)*LST + DG-8]*v8; s -= Lb[(i+7)*LST + DG-7]*v7;
            s -= Lb[(i+6)*LST + DG-6]*v6; s -= Lb[(i+5)*LST + DG-5]*v5;
            s -= Lb[(i+4)*LST + DG-4]*v4; s -= Lb[(i+3)*LST + DG-3]*v3;
            s -= Lb[(i+2)*LST + DG-2]*v2; s -= Lb[(i+1)*LST + DG-1]*v1;
            s *= iDf[i];
            cd[i] = s;
            v8=v7; v7=v6; v6=v5; v5=v4; v4=v3; v3=v2; v2=v1; v1=s;
        }
    }
    __syncthreads();

    // ---- Ef[a][k] = sum_i c_a[i] * P[i][k]  (1000 outputs x 50 FMA) ----
    for (int e = tid; e < 20*NR; e += 256) {
        int a = e / NR, k = e % NR;
        float s = 0.0f;
        #pragma unroll 10
        for (int i = 0; i < NR; ++i) s += CDf[a*51 + i] * Pf[i*51 + k];
        Ef[a*51 + k] = s;
    }
    __syncthreads();

    // ---- eps tile: ETf[r][c] = 0.5(tanhf(0.1 * Ef[r]·d_c) + 1) ----
    for (int e = tid; e < 20*20; e += 256) {
        int r = e / 20, c = e % 20;
        float s = 0.0f;
        #pragma unroll 10
        for (int k = 0; k < NR; ++k) s += Ef[r*51 + k] * CDf[(20+c)*51 + k];
        ETf[r*21 + c] = 0.5f * (tanhf(0.1f * s) + 1.0f);
    }
    __syncthreads();

    // ---- stencil derivatives + curvature penalty (fp32, fp64 accum) ----
    auto EXf = [&](int r, int k) -> float {
        int aab = a0 - 2 + r;
        if (aab == 0)      return (ETf[(r+1)*21+k] - ETf[r*21+k])     / g + SCADDF;
        if (aab == NP-1)   return (ETf[r*21+k]     - ETf[(r-1)*21+k]) / g + SCADDF;
        return (ETf[(r+1)*21+k] - ETf[(r-1)*21+k]) / (2.0f*g) + SCADDF;
    };
    auto EYf = [&](int r, int k) -> float {
        int bab = b0 - 2 + k;
        if (bab == 0)      return (ETf[r*21+k+1] - ETf[r*21+k])   / g + SCADDF;
        if (bab == NM-1)   return (ETf[r*21+k]   - ETf[r*21+k-1]) / g + SCADDF;
        return (ETf[r*21+k+1] - ETf[r*21+k-1]) / (2.0f*g) + SCADDF;
    };

    double local = 0.0;
    {
        const int aa = tid / 16, bb_ = tid % 16;
        const int a = a0 + aa, b = b0 + bb_;
        if (a < NP) {                               // b < NM always
            const int ar = aa + 2, kc = bb_ + 2;
            const float exv = EXf(ar, kc);
            const float eyv = EYf(ar, kc);
            float exx, exy, eyy;
            if (a == 0)         exx = (EXf(ar+1,kc) - EXf(ar,kc))   / g;
            else if (a == NP-1) exx = (EXf(ar,kc)   - EXf(ar-1,kc)) / g;
            else                exx = (EXf(ar+1,kc) - EXf(ar-1,kc)) / (2.0f*g);
            if (b == 0)         exy = (EXf(ar,kc+1) - EXf(ar,kc))   / g;
            else if (b == NM-1) exy = (EXf(ar,kc)   - EXf(ar,kc-1)) / g;
            else                exy = (EXf(ar,kc+1) - EXf(ar,kc-1)) / (2.0f*g);
            if (b == 0)         eyy = (EYf(ar,kc+1) - EYf(ar,kc))   / g;
            else if (b == NM-1) eyy = (EYf(ar,kc)   - EYf(ar,kc-1)) / g;
            else                eyy = (EYf(ar,kc+1) - EYf(ar,kc-1)) / (2.0f*g);

            float epsv = sqrtf(exv*exv + eyv*eyv);
            const float epsv_min = 1.6666667e-33f;  // 1e-32/6
            if (epsv < epsv_min) epsv = epsv_min;
            const float kk = (exv*exv*eyy - 2.0f*exv*eyv*exy + eyv*eyv*exx)
                             / (epsv*epsv*epsv);
            const float cc = fabsf(kk * atanf(epsv / ETf[ar*21+kc])) - pi_d;
            float v = fmaxf(cc, 0.0f) * g * g;
            if (!isnan(v)) local = (double)v;
        }
    }
    sdata[tid] = local;
    __syncthreads();
    for (int s = 128; s > 0; s >>= 1) {
        if (tid < s) sdata[tid] += sdata[tid + s];
        __syncthreads();
    }
    double* part = ws + OFF_PART;
    if (tid == 0) {
        part[blockIdx.x] = sdata[0];
        __threadfence();
        int old = atomicAdd((int*)(ws + OFF_CNT), 1);   // device-scope
        last = (old == NBLK_PEN - 1);
    }
    __syncthreads();
    if (last) {                                         // block-uniform branch
        __threadfence();
        double s = 0.0;
        for (int i = tid; i < NBLK_PEN; i += 256) s += part[i];  // fixed order
        sdata[tid] = s;
        __syncthreads();
        for (int w = 128; w > 0; w >>= 1) {
            if (tid < w) sdata[tid] += sdata[tid + w];
            __syncthreads();
        }
        if (tid == 0) out[0] = (float)sdata[0];
    }
}

extern "C" void kernel_launch(void* const* d_in, const int* in_sizes, int n_in,
                              void* d_out, int out_size, void* d_ws, size_t ws_size,
                              hipStream_t stream) {
    const float* params = (const float*)d_in[0];
    const float* x_rho  = (const float*)d_in[1];
    const float* y_rho  = (const float*)d_in[2];
    const float* x_phi  = (const float*)d_in[3];
    const float* y_phi  = (const float*)d_in[4];
    double* ws = (double*)d_ws;
    float* out = (float*)d_out;

    hipMemsetAsync((char*)d_ws + OFF_CNT*sizeof(double), 0, sizeof(int), stream);
    fused_kernel<<<NBLK_PEN, 256, 0, stream>>>(
        params, x_rho, y_rho, x_phi, y_phi, ws, out);
}

// Round 12
// 39.447 us; speedup vs baseline: 1.6036x; 1.1986x over previous
//
#include <hip/hip_runtime.h>
#include <math.h>

#define NR 50      // rho grid points per dim
#define NP 200     // phi grid points per dim
#define NM 400     // mirrored width (2*NP)
#define SCADDF 1e-12f
#define BW 6       // band of K (t=6 entry ~6e-13 rel) = band of L
#define LST 18     // L row stride: 0..9 margin zeros, 10..15 band t=6..1, 16 diag, 17 pad
#define DG 16
#define LROWS (NR + BW)
#define NCHOL 30   // exact Cholesky columns; 30..49 = Toeplitz steady state
#define RS 52      // row stride (floats) for 50-wide tables; 52%4==0 -> float4 rows
#define RS4 13     // row stride in float4

// ws layout (in doubles)
#define OFF_CNT  30000
#define OFF_PART 240000
#define NTA2 13           // a-tiles of 16 rows
#define NTB3 20           // b-tiles of 20 cols
#define NBLK (NTA2*NTB3)  // 260 blocks ~ 1/CU

// Single fused kernel, fp32 compute / fp64 accumulation.
// Per block: wave0 does band build + 30-column banded Cholesky + steady-state
// copy (Toeplitz); waves1-3 stage P and build the tile's 44 RBF table rows.
// Lanes 0..43 solve K v = rhs (sliding 6-reg window). Then float4 reg-tiled
// LDS GEMMs -> eps halo tile -> stencil curvature -> deterministic reduce.
__global__ __launch_bounds__(256) void fused_kernel(
        const float* __restrict__ params,
        const float* __restrict__ x_rho,
        const float* __restrict__ y_rho,
        const float* __restrict__ x_phi,
        const float* __restrict__ y_phi,
        double* __restrict__ ws,
        float* __restrict__ out) {
    __shared__ __align__(16) float Lb[LROWS * LST];
    __shared__ float iDf[NR];
    __shared__ __align__(16) float Pf [NR * RS];   // params, pads zeroed
    __shared__ __align__(16) float ATf[20 * RS];   // a-halo rows (clamped)
    __shared__ __align__(16) float BTf[24 * RS];   // b-halo rows (mirror+clamp)
    __shared__ __align__(16) float CDf[44 * RS];   // solved c(0..19)/d(20..43), pads zeroed
    __shared__ __align__(16) float Ef [20 * RS];   // E[a][k] = c_a^T P
    __shared__ float ETf[20 * 26];                 // eps halo tile (20a x 24b)
    __shared__ double sdata[256];
    __shared__ bool last;

    const int tid  = threadIdx.x;
    const int lane = tid & 63;
    const int ba = blockIdx.x / NTB3, bbt = blockIdx.x % NTB3;
    const int a0 = ba*16, b0 = bbt*20;

    const float Lr = y_rho[NR-1] - y_rho[0];
    const float sigma = 0.8f * Lr / (float)(NR - 1);
    const float inv2s2 = 1.0f / (2.0f * sigma * sigma);
    const float g = (x_phi[NP-1] - x_phi[0]) / (float)(NP - 1);
    const float pi_d = (float)(M_PI / 1.1);

    if (tid < 64) {
        // ---- wave 0: zero+build band, 30-col chol, steady-state copy ----
        for (int i = lane; i < LROWS*LST; i += 64) Lb[i] = 0.0f;
        for (int idx = lane; idx < NR*(BW+1); idx += 64) {
            int i = idx / (BW+1), t = idx % (BW+1);
            int k = i - t;
            if (k >= 0) {
                float d = y_rho[i] - y_rho[k];
                Lb[i*LST + DG - t] = expf(-d*d*inv2s2);
            }
        }
        for (int j = 0; j < NCHOL; ++j) {
            const int i = j + lane;
            float s = 0.0f;
            if (lane <= BW && i < NR) {
                s = Lb[i*LST + DG - lane];
                #pragma unroll
                for (int t = 1; t <= BW; ++t)       // margins absorb oob as 0
                    s -= Lb[i*LST + DG - lane - t] * Lb[j*LST + DG - t];
            }
            float dg = sqrtf(__shfl(s, 0, 64));     // lane 0 holds diag dot
            float invd = 1.0f / dg;
            if (lane <= BW && i < NR) {
                Lb[i*LST + DG - lane] = (lane == 0) ? dg : s * invd;
                if (lane == 0) iDf[j] = invd;
            }
        }
        // Toeplitz steady state: columns NCHOL..49 copy column NCHOL-1's band
        for (int e = lane; e < (NR-NCHOL)*(BW+1); e += 64) {
            int j = NCHOL + e / (BW+1), t = e % (BW+1);
            int i = j + t;
            if (i < NR) Lb[i*LST + DG - t] = Lb[(NCHOL-1+t)*LST + DG - t];
            if (t == 0) iDf[j] = iDf[NCHOL-1];
        }
    } else {
        // ---- waves 1-3 (overlap chol): stage P (pads zeroed) + tables ----
        for (int idx = tid - 64; idx < NR*NR; idx += 192)
            Pf[(idx/NR)*RS + (idx%NR)] = params[idx];
        for (int e = tid - 64; e < NR; e += 192) {
            Pf[e*RS + 50] = 0.0f; Pf[e*RS + 51] = 0.0f;
        }
        for (int e = tid - 64; e < 20*NR; e += 192) {
            int r = e / NR, iy = e % NR;
            int aab = a0 - 2 + r; aab = aab < 0 ? 0 : (aab > NP-1 ? NP-1 : aab);
            float da = y_phi[aab] - y_rho[iy];
            ATf[r*RS + iy] = expf(-da*da*inv2s2);
        }
        for (int e = tid - 64; e < 24*NR; e += 192) {
            int r = e / NR, iy = e % NR;
            int mb = b0 - 2 + r;  mb = mb < 0 ? 0 : (mb > NM-1 ? NM-1 : mb);
            int bb = (mb < NP) ? mb : (NM-1 - mb);   // mirror to base col
            float db = x_phi[bb] - x_rho[iy];
            BTf[r*RS + iy] = expf(-db*db*inv2s2);
        }
    }
    __syncthreads();

    // ---- lanes 0..43: solve K v = rhs, sliding 6-reg window ----
    if (tid < 44) {
        const float* rhs = (tid < 20) ? (ATf + tid*RS) : (BTf + (tid-20)*RS);
        float* cd = CDf + tid*RS;
        float w1=0,w2=0,w3=0,w4=0,w5=0,w6=0;
        #pragma unroll 2
        for (int i = 0; i < NR; ++i) {              // forward L y = rhs
            const float* Lr_ = Lb + i*LST + DG;
            float s = rhs[i];
            s -= Lr_[-6]*w6; s -= Lr_[-5]*w5; s -= Lr_[-4]*w4;
            s -= Lr_[-3]*w3; s -= Lr_[-2]*w2; s -= Lr_[-1]*w1;
            s *= iDf[i];
            cd[i] = s;
            w6=w5; w5=w4; w4=w3; w3=w2; w2=w1; w1=s;
        }
        float v1=0,v2=0,v3=0,v4=0,v5=0,v6=0;
        #pragma unroll 2
        for (int i = NR-1; i >= 0; --i) {           // backward L^T x = y
            float s = cd[i];
            s -= Lb[(i+6)*LST + DG-6]*v6; s -= Lb[(i+5)*LST + DG-5]*v5;
            s -= Lb[(i+4)*LST + DG-4]*v4; s -= Lb[(i+3)*LST + DG-3]*v3;
            s -= Lb[(i+2)*LST + DG-2]*v2; s -= Lb[(i+1)*LST + DG-1]*v1;
            s *= iDf[i];
            cd[i] = s;
            v6=v5; v5=v4; v4=v3; v3=v2; v2=v1; v1=s;
        }
        cd[50] = 0.0f; cd[51] = 0.0f;               // zero pad for float4 dots
    }
    __syncthreads();

    // ---- Ef[a][k] = sum_i c_a[i]*P[i][k] : float4 micro-tile (20x13 units) --
    {
        const float4* Pf4 = reinterpret_cast<const float4*>(Pf);
        float4* Ef4 = reinterpret_cast<float4*>(Ef);
        for (int u = tid; u < 20*RS4; u += 256) {
            int a = u / RS4, k4 = u % RS4;
            float4 acc = make_float4(0.f, 0.f, 0.f, 0.f);
            #pragma unroll 10
            for (int i = 0; i < NR; ++i) {
                float c = CDf[a*RS + i];
                float4 p = Pf4[i*RS4 + k4];
                acc.x += c*p.x; acc.y += c*p.y; acc.z += c*p.z; acc.w += c*p.w;
            }
            Ef4[a*RS4 + k4] = acc;
        }
    }
    __syncthreads();

    // ---- eps halo tile: ETf[r][c] = act( Ef[r] . d_c ) via float4 dots ----
    {
        const float4* Ef4 = reinterpret_cast<const float4*>(Ef);
        const float4* CD4 = reinterpret_cast<const float4*>(CDf);
        for (int u = tid; u < 20*24; u += 256) {
            int r = u / 24, c = u % 24;
            const float4* e4 = Ef4 + r*RS4;
            const float4* d4 = CD4 + (20+c)*RS4;
            float s = 0.0f;
            #pragma unroll
            for (int k4 = 0; k4 < RS4; ++k4) {
                float4 a = e4[k4], b = d4[k4];
                s += a.x*b.x + a.y*b.y + a.z*b.z + a.w*b.w;
            }
            ETf[r*26 + c] = 0.5f * (tanhf(0.1f * s) + 1.0f);
        }
    }
    __syncthreads();

    // ---- stencil derivatives + curvature penalty (fp32, fp64 accum) ----
    auto EXf = [&](int r, int k) -> float {
        int aab = a0 - 2 + r;
        if (aab == 0)      return (ETf[(r+1)*26+k] - ETf[r*26+k])     / g + SCADDF;
        if (aab == NP-1)   return (ETf[r*26+k]     - ETf[(r-1)*26+k]) / g + SCADDF;
        return (ETf[(r+1)*26+k] - ETf[(r-1)*26+k]) / (2.0f*g) + SCADDF;
    };
    auto EYf = [&](int r, int k) -> float {
        int bab = b0 - 2 + k;
        if (bab == 0)      return (ETf[r*26+k+1] - ETf[r*26+k])   / g + SCADDF;
        if (bab == NM-1)   return (ETf[r*26+k]   - ETf[r*26+k-1]) / g + SCADDF;
        return (ETf[r*26+k+1] - ETf[r*26+k-1]) / (2.0f*g) + SCADDF;
    };

    double local = 0.0;
    for (int u = tid; u < 16*20; u += 256) {        // 320 outputs, fixed order
        const int aa = u / 20, bb_ = u % 20;
        const int a = a0 + aa, b = b0 + bb_;
        if (a < NP) {                               // b < NM always
            const int ar = aa + 2, kc = bb_ + 2;
            const float exv = EXf(ar, kc);
            const float eyv = EYf(ar, kc);
            float exx, exy, eyy;
            if (a == 0)         exx = (EXf(ar+1,kc) - EXf(ar,kc))   / g;
            else if (a == NP-1) exx = (EXf(ar,kc)   - EXf(ar-1,kc)) / g;
            else                exx = (EXf(ar+1,kc) - EXf(ar-1,kc)) / (2.0f*g);
            if (b == 0)         exy = (EXf(ar,kc+1) - EXf(ar,kc))   / g;
            else if (b == NM-1) exy = (EXf(ar,kc)   - EXf(ar,kc-1)) / g;
            else                exy = (EXf(ar,kc+1) - EXf(ar,kc-1)) / (2.0f*g);
            if (b == 0)         eyy = (EYf(ar,kc+1) - EYf(ar,kc))   / g;
            else if (b == NM-1) eyy = (EYf(ar,kc)   - EYf(ar,kc-1)) / g;
            else                eyy = (EYf(ar,kc+1) - EYf(ar,kc-1)) / (2.0f*g);

            float epsv = sqrtf(exv*exv + eyv*eyv);
            const float epsv_min = 1.6666667e-33f;  // 1e-32/6
            if (epsv < epsv_min) epsv = epsv_min;
            const float kk = (exv*exv*eyy - 2.0f*exv*eyv*exy + eyv*eyv*exx)
                             / (epsv*epsv*epsv);
            const float cc = fabsf(kk * atanf(epsv / ETf[ar*26+kc])) - pi_d;
            float v = fmaxf(cc, 0.0f) * g * g;
            if (!isnan(v)) local += (double)v;
        }
    }
    sdata[tid] = local;
    __syncthreads();
    for (int s = 128; s > 0; s >>= 1) {
        if (tid < s) sdata[tid] += sdata[tid + s];
        __syncthreads();
    }
    double* part = ws + OFF_PART;
    if (tid == 0) {
        part[blockIdx.x] = sdata[0];
        __threadfence();
        int old = atomicAdd((int*)(ws + OFF_CNT), 1);   // device-scope
        last = (old == NBLK - 1);
    }
    __syncthreads();
    if (last) {                                         // block-uniform branch
        __threadfence();
        double s = 0.0;
        for (int i = tid; i < NBLK; i += 256) s += part[i];  // fixed order
        sdata[tid] = s;
        __syncthreads();
        for (int w = 128; w > 0; w >>= 1) {
            if (tid < w) sdata[tid] += sdata[tid + w];
            __syncthreads();
        }
        if (tid == 0) out[0] = (float)sdata[0];
    }
}

extern "C" void kernel_launch(void* const* d_in, const int* in_sizes, int n_in,
                              void* d_out, int out_size, void* d_ws, size_t ws_size,
                              hipStream_t stream) {
    const float* params = (const float*)d_in[0];
    const float* x_rho  = (const float*)d_in[1];
    const float* y_rho  = (const float*)d_in[2];
    const float* x_phi  = (const float*)d_in[3];
    const float* y_phi  = (const float*)d_in[4];
    double* ws = (double*)d_ws;
    float* out = (float*)d_out;

    hipMemsetAsync((char*)d_ws + OFF_CNT*sizeof(double), 0, sizeof(int), stream);
    fused_kernel<<<NBLK, 256, 0, stream>>>(
        params, x_rho, y_rho, x_phi, y_phi, ws, out);
}

// Round 13
// 32.108 us; speedup vs baseline: 1.9701x; 1.2285x over previous
//
#include <hip/hip_runtime.h>
#include <math.h>

#define NR 50      // rho grid points per dim
#define NP 200     // phi grid points per dim
#define NM 400     // mirrored width (2*NP)
#define SCADDF 1e-12f
#define BW 6       // band of K (t=6 entry ~6e-13 rel) = band of L
#define LST 18     // L row stride: 0..9 margin zeros, 10..15 band t=6..1, 16 diag, 17 pad
#define DG 16
#define LROWS (NR + BW)
#define NCHOL 30   // exact Cholesky columns; 30..49 = Toeplitz steady state
#define RS 52      // row stride (floats); 52%4==0 -> float4 rows
#define RS4 13     // row stride in float4

// ws layout (in doubles)
#define OFF_PART 240000
#define NTA2 13           // a-tiles of 16 rows
#define NTB3 20           // b-tiles of 20 cols
#define NBLK (NTA2*NTB3)  // 260 blocks ~ 1/CU

// Penalty kernel: R12's fused compute verbatim, but the exit is a plain
// partial-store (no memset-armed counter, no threadfence, no atomic funnel,
// no last-block spin). A separate 1-block finalize does the deterministic sum.
__global__ __launch_bounds__(256) void penalty_kernel(
        const float* __restrict__ params,
        const float* __restrict__ x_rho,
        const float* __restrict__ y_rho,
        const float* __restrict__ x_phi,
        const float* __restrict__ y_phi,
        double* __restrict__ ws) {
    __shared__ __align__(16) float Lb[LROWS * LST];
    __shared__ float iDf[NR];
    __shared__ __align__(16) float Pf [NR * RS];   // params, pads zeroed
    __shared__ __align__(16) float ATf[20 * RS];   // a-halo rows (clamped)
    __shared__ __align__(16) float BTf[24 * RS];   // b-halo rows (mirror+clamp)
    __shared__ __align__(16) float CDf[44 * RS];   // solved c(0..19)/d(20..43)
    __shared__ __align__(16) float Ef [20 * RS];   // E[a][k] = c_a^T P
    __shared__ float ETf[20 * 26];                 // eps halo tile (20a x 24b)
    __shared__ double sdata[256];

    const int tid  = threadIdx.x;
    const int lane = tid & 63;
    const int ba = blockIdx.x / NTB3, bbt = blockIdx.x % NTB3;
    const int a0 = ba*16, b0 = bbt*20;

    const float Lr = y_rho[NR-1] - y_rho[0];
    const float sigma = 0.8f * Lr / (float)(NR - 1);
    const float inv2s2 = 1.0f / (2.0f * sigma * sigma);
    const float g = (x_phi[NP-1] - x_phi[0]) / (float)(NP - 1);
    const float pi_d = (float)(M_PI / 1.1);

    if (tid < 64) {
        // ---- wave 0: zero+build band, 30-col chol, steady-state copy ----
        for (int i = lane; i < LROWS*LST; i += 64) Lb[i] = 0.0f;
        for (int idx = lane; idx < NR*(BW+1); idx += 64) {
            int i = idx / (BW+1), t = idx % (BW+1);
            int k = i - t;
            if (k >= 0) {
                float d = y_rho[i] - y_rho[k];
                Lb[i*LST + DG - t] = expf(-d*d*inv2s2);
            }
        }
        for (int j = 0; j < NCHOL; ++j) {
            const int i = j + lane;
            float s = 0.0f;
            if (lane <= BW && i < NR) {
                s = Lb[i*LST + DG - lane];
                #pragma unroll
                for (int t = 1; t <= BW; ++t)       // margins absorb oob as 0
                    s -= Lb[i*LST + DG - lane - t] * Lb[j*LST + DG - t];
            }
            float dg = sqrtf(__shfl(s, 0, 64));     // lane 0 holds diag dot
            float invd = 1.0f / dg;
            if (lane <= BW && i < NR) {
                Lb[i*LST + DG - lane] = (lane == 0) ? dg : s * invd;
                if (lane == 0) iDf[j] = invd;
            }
        }
        // Toeplitz steady state: columns NCHOL..49 copy column NCHOL-1's band
        for (int e = lane; e < (NR-NCHOL)*(BW+1); e += 64) {
            int j = NCHOL + e / (BW+1), t = e % (BW+1);
            int i = j + t;
            if (i < NR) Lb[i*LST + DG - t] = Lb[(NCHOL-1+t)*LST + DG - t];
            if (t == 0) iDf[j] = iDf[NCHOL-1];
        }
    } else {
        // ---- waves 1-3 (overlap chol): stage P (pads zeroed) + tables ----
        for (int idx = tid - 64; idx < NR*NR; idx += 192)
            Pf[(idx/NR)*RS + (idx%NR)] = params[idx];
        for (int e = tid - 64; e < NR; e += 192) {
            Pf[e*RS + 50] = 0.0f; Pf[e*RS + 51] = 0.0f;
        }
        for (int e = tid - 64; e < 20*NR; e += 192) {
            int r = e / NR, iy = e % NR;
            int aab = a0 - 2 + r; aab = aab < 0 ? 0 : (aab > NP-1 ? NP-1 : aab);
            float da = y_phi[aab] - y_rho[iy];
            ATf[r*RS + iy] = expf(-da*da*inv2s2);
        }
        for (int e = tid - 64; e < 24*NR; e += 192) {
            int r = e / NR, iy = e % NR;
            int mb = b0 - 2 + r;  mb = mb < 0 ? 0 : (mb > NM-1 ? NM-1 : mb);
            int bb = (mb < NP) ? mb : (NM-1 - mb);   // mirror to base col
            float db = x_phi[bb] - x_rho[iy];
            BTf[r*RS + iy] = expf(-db*db*inv2s2);
        }
    }
    __syncthreads();

    // ---- lanes 0..43: solve K v = rhs, sliding 6-reg window ----
    if (tid < 44) {
        const float* rhs = (tid < 20) ? (ATf + tid*RS) : (BTf + (tid-20)*RS);
        float* cd = CDf + tid*RS;
        float w1=0,w2=0,w3=0,w4=0,w5=0,w6=0;
        #pragma unroll 2
        for (int i = 0; i < NR; ++i) {              // forward L y = rhs
            const float* Lr_ = Lb + i*LST + DG;
            float s = rhs[i];
            s -= Lr_[-6]*w6; s -= Lr_[-5]*w5; s -= Lr_[-4]*w4;
            s -= Lr_[-3]*w3; s -= Lr_[-2]*w2; s -= Lr_[-1]*w1;
            s *= iDf[i];
            cd[i] = s;
            w6=w5; w5=w4; w4=w3; w3=w2; w2=w1; w1=s;
        }
        float v1=0,v2=0,v3=0,v4=0,v5=0,v6=0;
        #pragma unroll 2
        for (int i = NR-1; i >= 0; --i) {           // backward L^T x = y
            float s = cd[i];
            s -= Lb[(i+6)*LST + DG-6]*v6; s -= Lb[(i+5)*LST + DG-5]*v5;
            s -= Lb[(i+4)*LST + DG-4]*v4; s -= Lb[(i+3)*LST + DG-3]*v3;
            s -= Lb[(i+2)*LST + DG-2]*v2; s -= Lb[(i+1)*LST + DG-1]*v1;
            s *= iDf[i];
            cd[i] = s;
            v6=v5; v5=v4; v4=v3; v3=v2; v2=v1; v1=s;
        }
        cd[50] = 0.0f; cd[51] = 0.0f;               // zero pad for float4 dots
    }
    __syncthreads();

    // ---- Ef[a][k] = sum_i c_a[i]*P[i][k] : float4 micro-tile ----
    {
        const float4* Pf4 = reinterpret_cast<const float4*>(Pf);
        float4* Ef4 = reinterpret_cast<float4*>(Ef);
        for (int u = tid; u < 20*RS4; u += 256) {
            int a = u / RS4, k4 = u % RS4;
            float4 acc = make_float4(0.f, 0.f, 0.f, 0.f);
            #pragma unroll 10
            for (int i = 0; i < NR; ++i) {
                float c = CDf[a*RS + i];
                float4 p = Pf4[i*RS4 + k4];
                acc.x += c*p.x; acc.y += c*p.y; acc.z += c*p.z; acc.w += c*p.w;
            }
            Ef4[a*RS4 + k4] = acc;
        }
    }
    __syncthreads();

    // ---- eps halo tile: ETf[r][c] = act( Ef[r] . d_c ) via float4 dots ----
    {
        const float4* Ef4 = reinterpret_cast<const float4*>(Ef);
        const float4* CD4 = reinterpret_cast<const float4*>(CDf);
        for (int u = tid; u < 20*24; u += 256) {
            int r = u / 24, c = u % 24;
            const float4* e4 = Ef4 + r*RS4;
            const float4* d4 = CD4 + (20+c)*RS4;
            float s = 0.0f;
            #pragma unroll
            for (int k4 = 0; k4 < RS4; ++k4) {
                float4 a = e4[k4], b = d4[k4];
                s += a.x*b.x + a.y*b.y + a.z*b.z + a.w*b.w;
            }
            ETf[r*26 + c] = 0.5f * (tanhf(0.1f * s) + 1.0f);
        }
    }
    __syncthreads();

    // ---- stencil derivatives + curvature penalty (fp32, fp64 accum) ----
    auto EXf = [&](int r, int k) -> float {
        int aab = a0 - 2 + r;
        if (aab == 0)      return (ETf[(r+1)*26+k] - ETf[r*26+k])     / g + SCADDF;
        if (aab == NP-1)   return (ETf[r*26+k]     - ETf[(r-1)*26+k]) / g + SCADDF;
        return (ETf[(r+1)*26+k] - ETf[(r-1)*26+k]) / (2.0f*g) + SCADDF;
    };
    auto EYf = [&](int r, int k) -> float {
        int bab = b0 - 2 + k;
        if (bab == 0)      return (ETf[r*26+k+1] - ETf[r*26+k])   / g + SCADDF;
        if (bab == NM-1)   return (ETf[r*26+k]   - ETf[r*26+k-1]) / g + SCADDF;
        return (ETf[r*26+k+1] - ETf[r*26+k-1]) / (2.0f*g) + SCADDF;
    };

    double local = 0.0;
    for (int u = tid; u < 16*20; u += 256) {        // 320 outputs, fixed order
        const int aa = u / 20, bb_ = u % 20;
        const int a = a0 + aa, b = b0 + bb_;
        if (a < NP) {                               // b < NM always
            const int ar = aa + 2, kc = bb_ + 2;
            const float exv = EXf(ar, kc);
            const float eyv = EYf(ar, kc);
            float exx, exy, eyy;
            if (a == 0)         exx = (EXf(ar+1,kc) - EXf(ar,kc))   / g;
            else if (a == NP-1) exx = (EXf(ar,kc)   - EXf(ar-1,kc)) / g;
            else                exx = (EXf(ar+1,kc) - EXf(ar-1,kc)) / (2.0f*g);
            if (b == 0)         exy = (EXf(ar,kc+1) - EXf(ar,kc))   / g;
            else if (b == NM-1) exy = (EXf(ar,kc)   - EXf(ar,kc-1)) / g;
            else                exy = (EXf(ar,kc+1) - EXf(ar,kc-1)) / (2.0f*g);
            if (b == 0)         eyy = (EYf(ar,kc+1) - EYf(ar,kc))   / g;
            else if (b == NM-1) eyy = (EYf(ar,kc)   - EYf(ar,kc-1)) / g;
            else                eyy = (EYf(ar,kc+1) - EYf(ar,kc-1)) / (2.0f*g);

            float epsv = sqrtf(exv*exv + eyv*eyv);
            const float epsv_min = 1.6666667e-33f;  // 1e-32/6
            if (epsv < epsv_min) epsv = epsv_min;
            const float kk = (exv*exv*eyy - 2.0f*exv*eyv*exy + eyv*eyv*exx)
                             / (epsv*epsv*epsv);
            const float cc = fabsf(kk * atanf(epsv / ETf[ar*26+kc])) - pi_d;
            float v = fmaxf(cc, 0.0f) * g * g;
            if (!isnan(v)) local += (double)v;
        }
    }
    sdata[tid] = local;
    __syncthreads();
    for (int s = 128; s > 0; s >>= 1) {
        if (tid < s) sdata[tid] += sdata[tid + s];
        __syncthreads();
    }
    if (tid == 0) (ws + OFF_PART)[blockIdx.x] = sdata[0];   // plain store, done
}

// ---------------- finalize: 1 block, fixed-order deterministic sum ----------
__global__ __launch_bounds__(256) void finalize_kernel(
        const double* __restrict__ ws, float* __restrict__ out) {
    __shared__ double sdata[256];
    const double* part = ws + OFF_PART;
    const int t = threadIdx.x;
    double s = 0.0;
    for (int i = t; i < NBLK; i += 256) s += part[i];       // fixed order
    sdata[t] = s;
    __syncthreads();
    for (int w = 128; w > 0; w >>= 1) {
        if (t < w) sdata[t] += sdata[t + w];
        __syncthreads();
    }
    if (t == 0) out[0] = (float)sdata[0];
}

extern "C" void kernel_launch(void* const* d_in, const int* in_sizes, int n_in,
                              void* d_out, int out_size, void* d_ws, size_t ws_size,
                              hipStream_t stream) {
    const float* params = (const float*)d_in[0];
    const float* x_rho  = (const float*)d_in[1];
    const float* y_rho  = (const float*)d_in[2];
    const float* x_phi  = (const float*)d_in[3];
    const float* y_phi  = (const float*)d_in[4];
    double* ws = (double*)d_ws;
    float* out = (float*)d_out;

    penalty_kernel<<<NBLK, 256, 0, stream>>>(
        params, x_rho, y_rho, x_phi, y_phi, ws);
    finalize_kernel<<<1, 256, 0, stream>>>(ws, out);
}

// Round 14
// 31.129 us; speedup vs baseline: 2.0320x; 1.0314x over previous
//
#include <hip/hip_runtime.h>
#include <math.h>

#define NR 50      // rho grid points per dim
#define NP 200     // phi grid points per dim
#define NM 400     // mirrored width (2*NP)
#define SCADDF 1e-12f
#define BW 6       // band of K (t=6 entry ~6e-13 rel) = band of L
#define LST 18     // L row stride: margins zero, band t=6..1 at DG-6..DG-1, diag at DG
#define DG 16
#define LROWS (NR + BW)
#define NCHOL 30   // exact Cholesky columns; rest = Toeplitz steady state
#define RS 52      // row stride (floats); 52%4==0 -> float4 rows
#define RS4 13     // row stride in float4

// ws layout (in doubles)
#define OFF_PART 240000
#define NTA2 13           // a-tiles of 16 rows
#define NTB3 20           // b-tiles of 20 cols
#define NBLK (NTA2*NTB3)  // 260 blocks ~ 1/CU

// Penalty kernel. vs R13: (1) Cholesky runs entirely in registers via lane
// shuffles (Toeplitz band) — LDS only for off-chain publishes; (2) block
// reduction is per-wave shfl + 1 barrier instead of an 8-barrier LDS tree.
__global__ __launch_bounds__(256) void penalty_kernel(
        const float* __restrict__ params,
        const float* __restrict__ x_rho,
        const float* __restrict__ y_rho,
        const float* __restrict__ x_phi,
        const float* __restrict__ y_phi,
        double* __restrict__ ws) {
    __shared__ __align__(16) float Lb[LROWS * LST];
    __shared__ float iDf[NR];
    __shared__ __align__(16) float Pf [NR * RS];   // params, pads zeroed
    __shared__ __align__(16) float ATf[20 * RS];   // a-halo rows (clamped)
    __shared__ __align__(16) float BTf[24 * RS];   // b-halo rows (mirror+clamp)
    __shared__ __align__(16) float CDf[44 * RS];   // solved c(0..19)/d(20..43)
    __shared__ __align__(16) float Ef [20 * RS];   // E[a][k] = c_a^T P
    __shared__ float ETf[20 * 26];                 // eps halo tile (20a x 24b)
    __shared__ double wsum[4];

    const int tid  = threadIdx.x;
    const int lane = tid & 63;
    const int ba = blockIdx.x / NTB3, bbt = blockIdx.x % NTB3;
    const int a0 = ba*16, b0 = bbt*20;

    const float Lr = y_rho[NR-1] - y_rho[0];
    const float sigma = 0.8f * Lr / (float)(NR - 1);
    const float inv2s2 = 1.0f / (2.0f * sigma * sigma);
    const float g = (x_phi[NP-1] - x_phi[0]) / (float)(NP - 1);
    const float pi_d = (float)(M_PI / 1.1);

    if (tid < 64) {
        // ---- wave 0: register/shuffle banded Cholesky (Toeplitz band) ----
        for (int i = lane; i < LROWS*LST; i += 64) Lb[i] = 0.0f;
        const int t = lane;
        float ct = 0.0f;
        if (t <= BW) {
            float d = y_rho[t] - y_rho[0];          // Toeplitz coefficient c_t
            ct = expf(-d*d*inv2s2);
        }
        float h1=0,h2=0,h3=0,h4=0,h5=0,h6=0;        // last-6-column history
        for (int j = 0; j < NCHOL; ++j) {
            float s = ct;
            // s -= L[j+t][j-u] * L[j][j-u],  u=1..6
            s -= __shfl(h1, t+1, 64) * __shfl(h1, 1, 64);
            s -= __shfl(h2, t+2, 64) * __shfl(h2, 2, 64);
            s -= __shfl(h3, t+3, 64) * __shfl(h3, 3, 64);
            s -= __shfl(h4, t+4, 64) * __shfl(h4, 4, 64);
            s -= __shfl(h5, t+5, 64) * __shfl(h5, 5, 64);
            s -= __shfl(h6, t+6, 64) * __shfl(h6, 6, 64);
            float dgdot = __shfl(s, 0, 64);         // lane 0 holds diag dot
            float dgv = sqrtf(dgdot);
            float invd = 1.0f / dgv;
            float nv = 0.0f;
            if (t <= BW && j + t < NR) {
                nv = (t == 0) ? dgv : s * invd;
                Lb[(j+t)*LST + DG - t] = nv;        // off-chain publish
            }
            if (t == 0) iDf[j] = invd;
            h6=h5; h5=h4; h4=h3; h3=h2; h2=h1; h1=nv;
        }
        // Toeplitz steady state: columns NCHOL..NR-1 reuse col NCHOL-1's band
        float steady = h1;
        float invdS = 1.0f / __shfl(h1, 0, 64);
        for (int j = NCHOL; j < NR; ++j) {
            if (t <= BW && j + t < NR)
                Lb[(j+t)*LST + DG - t] = steady;
            if (t == 0) iDf[j] = invdS;
        }
    } else {
        // ---- waves 1-3 (overlap chol): stage P (pads zeroed) + tables ----
        for (int idx = tid - 64; idx < NR*NR; idx += 192)
            Pf[(idx/NR)*RS + (idx%NR)] = params[idx];
        for (int e = tid - 64; e < NR; e += 192) {
            Pf[e*RS + 50] = 0.0f; Pf[e*RS + 51] = 0.0f;
        }
        for (int e = tid - 64; e < 20*NR; e += 192) {
            int r = e / NR, iy = e % NR;
            int aab = a0 - 2 + r; aab = aab < 0 ? 0 : (aab > NP-1 ? NP-1 : aab);
            float da = y_phi[aab] - y_rho[iy];
            ATf[r*RS + iy] = expf(-da*da*inv2s2);
        }
        for (int e = tid - 64; e < 24*NR; e += 192) {
            int r = e / NR, iy = e % NR;
            int mb = b0 - 2 + r;  mb = mb < 0 ? 0 : (mb > NM-1 ? NM-1 : mb);
            int bb = (mb < NP) ? mb : (NM-1 - mb);   // mirror to base col
            float db = x_phi[bb] - x_rho[iy];
            BTf[r*RS + iy] = expf(-db*db*inv2s2);
        }
    }
    __syncthreads();

    // ---- lanes 0..43: solve K v = rhs, sliding 6-reg window ----
    if (tid < 44) {
        const float* rhs = (tid < 20) ? (ATf + tid*RS) : (BTf + (tid-20)*RS);
        float* cd = CDf + tid*RS;
        float w1=0,w2=0,w3=0,w4=0,w5=0,w6=0;
        #pragma unroll 2
        for (int i = 0; i < NR; ++i) {              // forward L y = rhs
            const float* Lr_ = Lb + i*LST + DG;
            float s = rhs[i];
            s -= Lr_[-6]*w6; s -= Lr_[-5]*w5; s -= Lr_[-4]*w4;
            s -= Lr_[-3]*w3; s -= Lr_[-2]*w2; s -= Lr_[-1]*w1;
            s *= iDf[i];
            cd[i] = s;
            w6=w5; w5=w4; w4=w3; w3=w2; w2=w1; w1=s;
        }
        float v1=0,v2=0,v3=0,v4=0,v5=0,v6=0;
        #pragma unroll 2
        for (int i = NR-1; i >= 0; --i) {           // backward L^T x = y
            float s = cd[i];
            s -= Lb[(i+6)*LST + DG-6]*v6; s -= Lb[(i+5)*LST + DG-5]*v5;
            s -= Lb[(i+4)*LST + DG-4]*v4; s -= Lb[(i+3)*LST + DG-3]*v3;
            s -= Lb[(i+2)*LST + DG-2]*v2; s -= Lb[(i+1)*LST + DG-1]*v1;
            s *= iDf[i];
            cd[i] = s;
            v6=v5; v5=v4; v4=v3; v3=v2; v2=v1; v1=s;
        }
        cd[50] = 0.0f; cd[51] = 0.0f;               // zero pad for float4 dots
    }
    __syncthreads();

    // ---- Ef[a][k] = sum_i c_a[i]*P[i][k] : float4 micro-tile ----
    {
        const float4* Pf4 = reinterpret_cast<const float4*>(Pf);
        float4* Ef4 = reinterpret_cast<float4*>(Ef);
        for (int u = tid; u < 20*RS4; u += 256) {
            int a = u / RS4, k4 = u % RS4;
            float4 acc = make_float4(0.f, 0.f, 0.f, 0.f);
            #pragma unroll 10
            for (int i = 0; i < NR; ++i) {
                float c = CDf[a*RS + i];
                float4 p = Pf4[i*RS4 + k4];
                acc.x += c*p.x; acc.y += c*p.y; acc.z += c*p.z; acc.w += c*p.w;
            }
            Ef4[a*RS4 + k4] = acc;
        }
    }
    __syncthreads();

    // ---- eps halo tile: ETf[r][c] = act( Ef[r] . d_c ) via float4 dots ----
    {
        const float4* Ef4 = reinterpret_cast<const float4*>(Ef);
        const float4* CD4 = reinterpret_cast<const float4*>(CDf);
        for (int u = tid; u < 20*24; u += 256) {
            int r = u / 24, c = u % 24;
            const float4* e4 = Ef4 + r*RS4;
            const float4* d4 = CD4 + (20+c)*RS4;
            float s = 0.0f;
            #pragma unroll
            for (int k4 = 0; k4 < RS4; ++k4) {
                float4 a = e4[k4], b = d4[k4];
                s += a.x*b.x + a.y*b.y + a.z*b.z + a.w*b.w;
            }
            ETf[r*26 + c] = 0.5f * (tanhf(0.1f * s) + 1.0f);
        }
    }
    __syncthreads();

    // ---- stencil derivatives + curvature penalty (fp32, fp64 accum) ----
    auto EXf = [&](int r, int k) -> float {
        int aab = a0 - 2 + r;
        if (aab == 0)      return (ETf[(r+1)*26+k] - ETf[r*26+k])     / g + SCADDF;
        if (aab == NP-1)   return (ETf[r*26+k]     - ETf[(r-1)*26+k]) / g + SCADDF;
        return (ETf[(r+1)*26+k] - ETf[(r-1)*26+k]) / (2.0f*g) + SCADDF;
    };
    auto EYf = [&](int r, int k) -> float {
        int bab = b0 - 2 + k;
        if (bab == 0)      return (ETf[r*26+k+1] - ETf[r*26+k])   / g + SCADDF;
        if (bab == NM-1)   return (ETf[r*26+k]   - ETf[r*26+k-1]) / g + SCADDF;
        return (ETf[r*26+k+1] - ETf[r*26+k-1]) / (2.0f*g) + SCADDF;
    };

    double local = 0.0;
    for (int u = tid; u < 16*20; u += 256) {        // 320 outputs, fixed order
        const int aa = u / 20, bb_ = u % 20;
        const int a = a0 + aa, b = b0 + bb_;
        if (a < NP) {                               // b < NM always
            const int ar = aa + 2, kc = bb_ + 2;
            const float exv = EXf(ar, kc);
            const float eyv = EYf(ar, kc);
            float exx, exy, eyy;
            if (a == 0)         exx = (EXf(ar+1,kc) - EXf(ar,kc))   / g;
            else if (a == NP-1) exx = (EXf(ar,kc)   - EXf(ar-1,kc)) / g;
            else                exx = (EXf(ar+1,kc) - EXf(ar-1,kc)) / (2.0f*g);
            if (b == 0)         exy = (EXf(ar,kc+1) - EXf(ar,kc))   / g;
            else if (b == NM-1) exy = (EXf(ar,kc)   - EXf(ar,kc-1)) / g;
            else                exy = (EXf(ar,kc+1) - EXf(ar,kc-1)) / (2.0f*g);
            if (b == 0)         eyy = (EYf(ar,kc+1) - EYf(ar,kc))   / g;
            else if (b == NM-1) eyy = (EYf(ar,kc)   - EYf(ar,kc-1)) / g;
            else                eyy = (EYf(ar,kc+1) - EYf(ar,kc-1)) / (2.0f*g);

            float epsv = sqrtf(exv*exv + eyv*eyv);
            const float epsv_min = 1.6666667e-33f;  // 1e-32/6
            if (epsv < epsv_min) epsv = epsv_min;
            const float kk = (exv*exv*eyy - 2.0f*exv*eyv*exy + eyv*eyv*exx)
                             / (epsv*epsv*epsv);
            const float cc = fabsf(kk * atanf(epsv / ETf[ar*26+kc])) - pi_d;
            float v = fmaxf(cc, 0.0f) * g * g;
            if (!isnan(v)) local += (double)v;
        }
    }

    // ---- per-wave shfl reduce (fixed tree) + single barrier ----
    #pragma unroll
    for (int off = 32; off > 0; off >>= 1)
        local += __shfl_down(local, off, 64);
    if (lane == 0) wsum[tid >> 6] = local;
    __syncthreads();
    if (tid == 0)
        (ws + OFF_PART)[blockIdx.x] = (wsum[0] + wsum[1]) + (wsum[2] + wsum[3]);
}

// ---------------- finalize: 1 block, fixed-order deterministic sum ----------
__global__ __launch_bounds__(256) void finalize_kernel(
        const double* __restrict__ ws, float* __restrict__ out) {
    __shared__ double sdata[256];
    const double* part = ws + OFF_PART;
    const int t = threadIdx.x;
    double s = 0.0;
    for (int i = t; i < NBLK; i += 256) s += part[i];       // fixed order
    sdata[t] = s;
    __syncthreads();
    for (int w = 128; w > 0; w >>= 1) {
        if (t < w) sdata[t] += sdata[t + w];
        __syncthreads();
    }
    if (t == 0) out[0] = (float)sdata[0];
}

extern "C" void kernel_launch(void* const* d_in, const int* in_sizes, int n_in,
                              void* d_out, int out_size, void* d_ws, size_t ws_size,
                              hipStream_t stream) {
    const float* params = (const float*)d_in[0];
    const float* x_rho  = (const float*)d_in[1];
    const float* y_rho  = (const float*)d_in[2];
    const float* x_phi  = (const float*)d_in[3];
    const float* y_phi  = (const float*)d_in[4];
    double* ws = (double*)d_ws;
    float* out = (float*)d_out;

    penalty_kernel<<<NBLK, 256, 0, stream>>>(
        params, x_rho, y_rho, x_phi, y_phi, ws);
    finalize_kernel<<<1, 256, 0, stream>>>(ws, out);
}

// Round 15
// 23.669 us; speedup vs baseline: 2.6726x; 1.3152x over previous
//
#include <hip/hip_runtime.h>
#include <math.h>

#define NR 50      // rho grid points per dim
#define NP 200     // phi grid points per dim
#define NM 400     // mirrored width (2*NP)
#define SCADDF 1e-12f
#define BW 4       // band of K in fp32 (c5,c6 < fp32 eps) = band of L
#define LST 18     // L row stride: band t=4..1 at DG-4..DG-1, diag at DG
#define DG 16
#define LROWS (NR + BW)
#define NCHOL 16   // exact chol columns; col-15 deviation from steady ~2e-6
#define RS 52      // row stride (floats); 52%4==0 -> float4 rows
#define RS4 13     // row stride in float4

// ws layout (in doubles)
#define OFF_PART 240000
#define NTA2 13           // a-tiles of 16 rows
#define NTB3 20           // b-tiles of 20 cols
#define NBLK (NTA2*NTB3)  // 260 blocks ~ 1/CU

// Penalty kernel. vs R14: BW=4 (fp32-exact), NCHOL=16, rsqrt-fused chol with
// freshest-term-last chains, steady-region solve runs on register coefficients
// (no LDS in the serial hot stretch).
__global__ __launch_bounds__(256) void penalty_kernel(
        const float* __restrict__ params,
        const float* __restrict__ x_rho,
        const float* __restrict__ y_rho,
        const float* __restrict__ x_phi,
        const float* __restrict__ y_phi,
        double* __restrict__ ws) {
    __shared__ __align__(16) float Lb[LROWS * LST];
    __shared__ float iDf[NR];
    __shared__ __align__(16) float Pf [NR * RS];   // params, pads zeroed
    __shared__ __align__(16) float ATf[20 * RS];   // a-halo rows (clamped)
    __shared__ __align__(16) float BTf[24 * RS];   // b-halo rows (mirror+clamp)
    __shared__ __align__(16) float CDf[44 * RS];   // solved c(0..19)/d(20..43)
    __shared__ __align__(16) float Ef [20 * RS];   // E[a][k] = c_a^T P
    __shared__ float ETf[20 * 26];                 // eps halo tile (20a x 24b)
    __shared__ double wsum[4];

    const int tid  = threadIdx.x;
    const int lane = tid & 63;
    const int ba = blockIdx.x / NTB3, bbt = blockIdx.x % NTB3;
    const int a0 = ba*16, b0 = bbt*20;

    const float Lr = y_rho[NR-1] - y_rho[0];
    const float sigma = 0.8f * Lr / (float)(NR - 1);
    const float inv2s2 = 1.0f / (2.0f * sigma * sigma);
    const float g = (x_phi[NP-1] - x_phi[0]) / (float)(NP - 1);
    const float pi_d = (float)(M_PI / 1.1);

    if (tid < 64) {
        // ---- wave 0: register/shuffle banded Cholesky (Toeplitz band) ----
        for (int i = lane; i < LROWS*LST; i += 64) Lb[i] = 0.0f;
        const int t = lane;
        float ct = 0.0f;
        if (t <= BW) {
            float d = y_rho[t] - y_rho[0];          // Toeplitz coefficient c_t
            ct = expf(-d*d*inv2s2);
        }
        float h1=0,h2=0,h3=0,h4=0;                  // last-4-column history
        float lastinv = 1.0f;
        for (int j = 0; j < NCHOL; ++j) {
            float s = ct;
            // oldest terms first; freshest (h1) last -> 2-op cross-col chain
            s -= __shfl(h4, t+4, 64) * __shfl(h4, 4, 64);
            s -= __shfl(h3, t+3, 64) * __shfl(h3, 3, 64);
            s -= __shfl(h2, t+2, 64) * __shfl(h2, 2, 64);
            s -= __shfl(h1, t+1, 64) * __shfl(h1, 1, 64);
            float invd = rsqrtf(__shfl(s, 0, 64));  // lane 0 holds diag dot
            float nv = 0.0f;
            if (t <= BW && j + t < NR) {
                nv = s * invd;                      // t=0: dgdot*rsqrt = sqrt
                Lb[(j+t)*LST + DG - t] = nv;
            }
            if (t == 0) iDf[j] = invd;
            lastinv = invd;
            h4=h3; h3=h2; h2=h1; h1=nv;
        }
        // Toeplitz steady state: columns NCHOL..NR-1 reuse col NCHOL-1's band
        float steady = h1;
        for (int j = NCHOL; j < NR; ++j) {
            if (t <= BW && j + t < NR)
                Lb[(j+t)*LST + DG - t] = steady;
            if (t == 0) iDf[j] = lastinv;
        }
    } else {
        // ---- waves 1-3 (overlap chol): stage P (pads zeroed) + tables ----
        for (int idx = tid - 64; idx < NR*NR; idx += 192)
            Pf[(idx/NR)*RS + (idx%NR)] = params[idx];
        for (int e = tid - 64; e < NR; e += 192) {
            Pf[e*RS + 50] = 0.0f; Pf[e*RS + 51] = 0.0f;
        }
        for (int e = tid - 64; e < 20*NR; e += 192) {
            int r = e / NR, iy = e % NR;
            int aab = a0 - 2 + r; aab = aab < 0 ? 0 : (aab > NP-1 ? NP-1 : aab);
            float da = y_phi[aab] - y_rho[iy];
            ATf[r*RS + iy] = expf(-da*da*inv2s2);
        }
        for (int e = tid - 64; e < 24*NR; e += 192) {
            int r = e / NR, iy = e % NR;
            int mb = b0 - 2 + r;  mb = mb < 0 ? 0 : (mb > NM-1 ? NM-1 : mb);
            int bb = (mb < NP) ? mb : (NM-1 - mb);   // mirror to base col
            float db = x_phi[bb] - x_rho[iy];
            BTf[r*RS + iy] = expf(-db*db*inv2s2);
        }
    }
    __syncthreads();

    // ---- lanes 0..43: solve K v = rhs, sliding 4-reg window ----
    if (tid < 44) {
        const float* rhs = (tid < 20) ? (ATf + tid*RS) : (BTf + (tid-20)*RS);
        float* cd = CDf + tid*RS;
        // steady-region coefficients in registers (rows/cols >= NCHOL)
        const float a1 = Lb[(NCHOL+1)*LST + DG - 1];
        const float a2 = Lb[(NCHOL+2)*LST + DG - 2];
        const float a3 = Lb[(NCHOL+3)*LST + DG - 3];
        const float a4 = Lb[(NCHOL+4)*LST + DG - 4];
        const float iDs = iDf[NCHOL];

        float w1=0,w2=0,w3=0,w4=0;
        for (int i = 0; i < NCHOL+4; ++i) {         // fwd boundary: LDS coeffs
            const float* Lr_ = Lb + i*LST + DG;
            float pre = rhs[i] - (Lr_[-4]*w4 + Lr_[-3]*w3);
            pre -= Lr_[-2]*w2;
            float s = (pre - Lr_[-1]*w1) * iDf[i];
            cd[i] = s;
            w4=w3; w3=w2; w2=w1; w1=s;
        }
        #pragma unroll 2
        for (int i = NCHOL+4; i < NR; ++i) {        // fwd steady: registers
            float pre = rhs[i] - (a4*w4 + a3*w3);
            pre -= a2*w2;
            float s = (pre - a1*w1) * iDs;
            cd[i] = s;
            w4=w3; w3=w2; w2=w1; w1=s;
        }
        float v1=0,v2=0,v3=0,v4=0;
        #pragma unroll 2
        for (int i = NR-1; i >= NCHOL; --i) {       // bwd steady: registers
            float pre = cd[i] - (a4*v4 + a3*v3);    // zero-init window = margin
            pre -= a2*v2;
            float s = (pre - a1*v1) * iDs;
            cd[i] = s;
            v4=v3; v3=v2; v2=v1; v1=s;
        }
        for (int i = NCHOL-1; i >= 0; --i) {        // bwd boundary: LDS coeffs
            float pre = cd[i] - (Lb[(i+4)*LST + DG-4]*v4 + Lb[(i+3)*LST + DG-3]*v3);
            pre -= Lb[(i+2)*LST + DG-2]*v2;
            float s = (pre - Lb[(i+1)*LST + DG-1]*v1) * iDf[i];
            cd[i] = s;
            v4=v3; v3=v2; v2=v1; v1=s;
        }
        cd[50] = 0.0f; cd[51] = 0.0f;               // zero pad for float4 dots
    }
    __syncthreads();

    // ---- Ef[a][k] = sum_i c_a[i]*P[i][k] : float4 micro-tile ----
    {
        const float4* Pf4 = reinterpret_cast<const float4*>(Pf);
        float4* Ef4 = reinterpret_cast<float4*>(Ef);
        for (int u = tid; u < 20*RS4; u += 256) {
            int a = u / RS4, k4 = u % RS4;
            float4 acc = make_float4(0.f, 0.f, 0.f, 0.f);
            #pragma unroll 10
            for (int i = 0; i < NR; ++i) {
                float c = CDf[a*RS + i];
                float4 p = Pf4[i*RS4 + k4];
                acc.x += c*p.x; acc.y += c*p.y; acc.z += c*p.z; acc.w += c*p.w;
            }
            Ef4[a*RS4 + k4] = acc;
        }
    }
    __syncthreads();

    // ---- eps halo tile: ETf[r][c] = act( Ef[r] . d_c ) via float4 dots ----
    {
        const float4* Ef4 = reinterpret_cast<const float4*>(Ef);
        const float4* CD4 = reinterpret_cast<const float4*>(CDf);
        for (int u = tid; u < 20*24; u += 256) {
            int r = u / 24, c = u % 24;
            const float4* e4 = Ef4 + r*RS4;
            const float4* d4 = CD4 + (20+c)*RS4;
            float s = 0.0f;
            #pragma unroll
            for (int k4 = 0; k4 < RS4; ++k4) {
                float4 a = e4[k4], b = d4[k4];
                s += a.x*b.x + a.y*b.y + a.z*b.z + a.w*b.w;
            }
            ETf[r*26 + c] = 0.5f * (tanhf(0.1f * s) + 1.0f);
        }
    }
    __syncthreads();

    // ---- stencil derivatives + curvature penalty (fp32, fp64 accum) ----
    auto EXf = [&](int r, int k) -> float {
        int aab = a0 - 2 + r;
        if (aab == 0)      return (ETf[(r+1)*26+k] - ETf[r*26+k])     / g + SCADDF;
        if (aab == NP-1)   return (ETf[r*26+k]     - ETf[(r-1)*26+k]) / g + SCADDF;
        return (ETf[(r+1)*26+k] - ETf[(r-1)*26+k]) / (2.0f*g) + SCADDF;
    };
    auto EYf = [&](int r, int k) -> float {
        int bab = b0 - 2 + k;
        if (bab == 0)      return (ETf[r*26+k+1] - ETf[r*26+k])   / g + SCADDF;
        if (bab == NM-1)   return (ETf[r*26+k]   - ETf[r*26+k-1]) / g + SCADDF;
        return (ETf[r*26+k+1] - ETf[r*26+k-1]) / (2.0f*g) + SCADDF;
    };

    double local = 0.0;
    for (int u = tid; u < 16*20; u += 256) {        // 320 outputs, fixed order
        const int aa = u / 20, bb_ = u % 20;
        const int a = a0 + aa, b = b0 + bb_;
        if (a < NP) {                               // b < NM always
            const int ar = aa + 2, kc = bb_ + 2;
            const float exv = EXf(ar, kc);
            const float eyv = EYf(ar, kc);
            float exx, exy, eyy;
            if (a == 0)         exx = (EXf(ar+1,kc) - EXf(ar,kc))   / g;
            else if (a == NP-1) exx = (EXf(ar,kc)   - EXf(ar-1,kc)) / g;
            else                exx = (EXf(ar+1,kc) - EXf(ar-1,kc)) / (2.0f*g);
            if (b == 0)         exy = (EXf(ar,kc+1) - EXf(ar,kc))   / g;
            else if (b == NM-1) exy = (EXf(ar,kc)   - EXf(ar,kc-1)) / g;
            else                exy = (EXf(ar,kc+1) - EXf(ar,kc-1)) / (2.0f*g);
            if (b == 0)         eyy = (EYf(ar,kc+1) - EYf(ar,kc))   / g;
            else if (b == NM-1) eyy = (EYf(ar,kc)   - EYf(ar,kc-1)) / g;
            else                eyy = (EYf(ar,kc+1) - EYf(ar,kc-1)) / (2.0f*g);

            float epsv = sqrtf(exv*exv + eyv*eyv);
            const float epsv_min = 1.6666667e-33f;  // 1e-32/6
            if (epsv < epsv_min) epsv = epsv_min;
            const float kk = (exv*exv*eyy - 2.0f*exv*eyv*exy + eyv*eyv*exx)
                             / (epsv*epsv*epsv);
            const float cc = fabsf(kk * atanf(epsv / ETf[ar*26+kc])) - pi_d;
            float v = fmaxf(cc, 0.0f) * g * g;
            if (!isnan(v)) local += (double)v;
        }
    }

    // ---- per-wave shfl reduce (fixed tree) + single barrier ----
    #pragma unroll
    for (int off = 32; off > 0; off >>= 1)
        local += __shfl_down(local, off, 64);
    if (lane == 0) wsum[tid >> 6] = local;
    __syncthreads();
    if (tid == 0)
        (ws + OFF_PART)[blockIdx.x] = (wsum[0] + wsum[1]) + (wsum[2] + wsum[3]);
}

// ---------------- finalize: 1 wave, shfl-only deterministic sum -------------
__global__ __launch_bounds__(64) void finalize_kernel(
        const double* __restrict__ ws, float* __restrict__ out) {
    const double* part = ws + OFF_PART;
    const int t = threadIdx.x;                       // 64 threads
    double s = 0.0;
    for (int i = t; i < NBLK; i += 64) s += part[i]; // fixed order
    #pragma unroll
    for (int off = 32; off > 0; off >>= 1)
        s += __shfl_down(s, off, 64);
    if (t == 0) out[0] = (float)s;
}

extern "C" void kernel_launch(void* const* d_in, const int* in_sizes, int n_in,
                              void* d_out, int out_size, void* d_ws, size_t ws_size,
                              hipStream_t stream) {
    const float* params = (const float*)d_in[0];
    const float* x_rho  = (const float*)d_in[1];
    const float* y_rho  = (const float*)d_in[2];
    const float* x_phi  = (const float*)d_in[3];
    const float* y_phi  = (const float*)d_in[4];
    double* ws = (double*)d_ws;
    float* out = (float*)d_out;

    penalty_kernel<<<NBLK, 256, 0, stream>>>(
        params, x_rho, y_rho, x_phi, y_phi, ws);
    finalize_kernel<<<1, 64, 0, stream>>>(ws, out);
}

// Round 16
// 23.427 us; speedup vs baseline: 2.7002x; 1.0103x over previous
//
#include <hip/hip_runtime.h>
#include <math.h>

#define NR 50      // rho grid points per dim
#define NP 200     // phi grid points per dim
#define NM 400     // mirrored width (2*NP)
#define SCADDF 1e-12f
#define BW 4       // band of K in fp32 (c5,c6 < fp32 eps) = band of L
#define LST 6      // L row stride: band t=4..1 at slots 0..3, diag at 4, pad at 5
#define DG 4
#define LROWS (NR + BW)
#define NCHOL 12   // exact chol columns; col-11 deviation from steady ~7e-5
#define RS 52      // row stride (floats); 52%4==0 -> float4 rows
#define RS4 13     // row stride in float4

// ws layout (in doubles)
#define OFF_PART 240000
#define NTA2 13           // a-tiles of 16 rows
#define NTB3 20           // b-tiles of 20 cols
#define NBLK (NTA2*NTB3)  // 260 blocks ~ 1/CU

// Penalty kernel. vs R15: dead K-band build removed (chol uses register
// Toeplitz coeffs only), steady-state copy trimmed to the 4 columns the solve
// actually reads, LST 18->6 (zero only rows 0..3), NCHOL 16->12.
__global__ __launch_bounds__(256) void penalty_kernel(
        const float* __restrict__ params,
        const float* __restrict__ x_rho,
        const float* __restrict__ y_rho,
        const float* __restrict__ x_phi,
        const float* __restrict__ y_phi,
        double* __restrict__ ws) {
    __shared__ __align__(16) float Lb[LROWS * LST];
    __shared__ float iDf[NR];
    __shared__ __align__(16) float Pf [NR * RS];   // params, pads zeroed
    __shared__ __align__(16) float ATf[20 * RS];   // a-halo rows (clamped)
    __shared__ __align__(16) float BTf[24 * RS];   // b-halo rows (mirror+clamp)
    __shared__ __align__(16) float CDf[44 * RS];   // solved c(0..19)/d(20..43)
    __shared__ __align__(16) float Ef [20 * RS];   // E[a][k] = c_a^T P
    __shared__ float ETf[20 * 26];                 // eps halo tile (20a x 24b)
    __shared__ double wsum[4];

    const int tid  = threadIdx.x;
    const int lane = tid & 63;
    const int ba = blockIdx.x / NTB3, bbt = blockIdx.x % NTB3;
    const int a0 = ba*16, b0 = bbt*20;

    const float Lr = y_rho[NR-1] - y_rho[0];
    const float sigma = 0.8f * Lr / (float)(NR - 1);
    const float inv2s2 = 1.0f / (2.0f * sigma * sigma);
    const float g = (x_phi[NP-1] - x_phi[0]) / (float)(NP - 1);
    const float pi_d = (float)(M_PI / 1.1);

    if (tid < 64) {
        // ---- wave 0: register/shuffle banded Cholesky (Toeplitz) ----
        const int t = lane;
        if (t < BW * LST) Lb[t] = 0.0f;             // zero rows 0..3 (junk cols j<0)
        float ct = 0.0f;
        if (t <= BW) {
            float d = y_rho[t] - y_rho[0];          // Toeplitz coefficient c_t
            ct = expf(-d*d*inv2s2);
        }
        float h1=0,h2=0,h3=0,h4=0;                  // last-4-column history
        float lastinv = 1.0f;
        for (int j = 0; j < NCHOL; ++j) {
            float s = ct;
            // oldest terms first; freshest (h1) last -> short cross-col chain
            s -= __shfl(h4, t+4, 64) * __shfl(h4, 4, 64);
            s -= __shfl(h3, t+3, 64) * __shfl(h3, 3, 64);
            s -= __shfl(h2, t+2, 64) * __shfl(h2, 2, 64);
            s -= __shfl(h1, t+1, 64) * __shfl(h1, 1, 64);
            float invd = rsqrtf(__shfl(s, 0, 64));  // lane 0 holds diag dot
            float nv = 0.0f;
            if (t <= BW && j + t < NR) {
                nv = s * invd;                      // t=0: dgdot*rsqrt = sqrt
                Lb[(j+t)*LST + DG - t] = nv;
            }
            if (t == 0) iDf[j] = invd;
            lastinv = invd;
            h4=h3; h3=h2; h2=h1; h1=nv;
        }
        // steady state: only cols NCHOL..NCHOL+3 are ever read by the solve
        float steady = h1;
        for (int j = NCHOL; j < NCHOL + 4; ++j) {
            if (t <= BW) Lb[(j+t)*LST + DG - t] = steady;
            if (t == 0)  iDf[j] = lastinv;
        }
        if (t == 0) iDf[NCHOL+4] = lastinv;         // (unused guard)
    } else {
        // ---- waves 1-3 (overlap chol): stage P (pads zeroed) + tables ----
        for (int idx = tid - 64; idx < NR*NR; idx += 192)
            Pf[(idx/NR)*RS + (idx%NR)] = params[idx];
        for (int e = tid - 64; e < NR; e += 192) {
            Pf[e*RS + 50] = 0.0f; Pf[e*RS + 51] = 0.0f;
        }
        for (int e = tid - 64; e < 20*NR; e += 192) {
            int r = e / NR, iy = e % NR;
            int aab = a0 - 2 + r; aab = aab < 0 ? 0 : (aab > NP-1 ? NP-1 : aab);
            float da = y_phi[aab] - y_rho[iy];
            ATf[r*RS + iy] = expf(-da*da*inv2s2);
        }
        for (int e = tid - 64; e < 24*NR; e += 192) {
            int r = e / NR, iy = e % NR;
            int mb = b0 - 2 + r;  mb = mb < 0 ? 0 : (mb > NM-1 ? NM-1 : mb);
            int bb = (mb < NP) ? mb : (NM-1 - mb);   // mirror to base col
            float db = x_phi[bb] - x_rho[iy];
            BTf[r*RS + iy] = expf(-db*db*inv2s2);
        }
    }
    __syncthreads();

    // ---- lanes 0..43: solve K v = rhs, sliding 4-reg window ----
    if (tid < 44) {
        const float* rhs = (tid < 20) ? (ATf + tid*RS) : (BTf + (tid-20)*RS);
        float* cd = CDf + tid*RS;
        // steady-region coefficients in registers (rows/cols >= NCHOL)
        const float a1 = Lb[(NCHOL+1)*LST + DG - 1];
        const float a2 = Lb[(NCHOL+2)*LST + DG - 2];
        const float a3 = Lb[(NCHOL+3)*LST + DG - 3];
        const float a4 = Lb[(NCHOL+4)*LST + DG - 4];
        const float iDs = iDf[NCHOL];

        float w1=0,w2=0,w3=0,w4=0;
        #pragma unroll 2
        for (int i = 0; i < NCHOL+4; ++i) {         // fwd boundary: LDS coeffs
            const float* Lr_ = Lb + i*LST + DG;
            float pre = rhs[i] - (Lr_[-4]*w4 + Lr_[-3]*w3);
            pre -= Lr_[-2]*w2;
            float s = (pre - Lr_[-1]*w1) * iDf[i];
            cd[i] = s;
            w4=w3; w3=w2; w2=w1; w1=s;
        }
        #pragma unroll 2
        for (int i = NCHOL+4; i < NR; ++i) {        // fwd steady: registers
            float pre = rhs[i] - (a4*w4 + a3*w3);
            pre -= a2*w2;
            float s = (pre - a1*w1) * iDs;
            cd[i] = s;
            w4=w3; w3=w2; w2=w1; w1=s;
        }
        float v1=0,v2=0,v3=0,v4=0;
        #pragma unroll 2
        for (int i = NR-1; i >= NCHOL; --i) {       // bwd steady: registers
            float pre = cd[i] - (a4*v4 + a3*v3);    // zero-init window = margin
            pre -= a2*v2;
            float s = (pre - a1*v1) * iDs;
            cd[i] = s;
            v4=v3; v3=v2; v2=v1; v1=s;
        }
        #pragma unroll 2
        for (int i = NCHOL-1; i >= 0; --i) {        // bwd boundary: LDS coeffs
            float pre = cd[i] - (Lb[(i+4)*LST + DG-4]*v4 + Lb[(i+3)*LST + DG-3]*v3);
            pre -= Lb[(i+2)*LST + DG-2]*v2;
            float s = (pre - Lb[(i+1)*LST + DG-1]*v1) * iDf[i];
            cd[i] = s;
            v4=v3; v3=v2; v2=v1; v1=s;
        }
        cd[50] = 0.0f; cd[51] = 0.0f;               // zero pad for float4 dots
    }
    __syncthreads();

    // ---- Ef[a][k] = sum_i c_a[i]*P[i][k] : float4 micro-tile ----
    {
        const float4* Pf4 = reinterpret_cast<const float4*>(Pf);
        float4* Ef4 = reinterpret_cast<float4*>(Ef);
        for (int u = tid; u < 20*RS4; u += 256) {
            int a = u / RS4, k4 = u % RS4;
            float4 acc = make_float4(0.f, 0.f, 0.f, 0.f);
            #pragma unroll 10
            for (int i = 0; i < NR; ++i) {
                float c = CDf[a*RS + i];
                float4 p = Pf4[i*RS4 + k4];
                acc.x += c*p.x; acc.y += c*p.y; acc.z += c*p.z; acc.w += c*p.w;
            }
            Ef4[a*RS4 + k4] = acc;
        }
    }
    __syncthreads();

    // ---- eps halo tile: ETf[r][c] = act( Ef[r] . d_c ) via float4 dots ----
    {
        const float4* Ef4 = reinterpret_cast<const float4*>(Ef);
        const float4* CD4 = reinterpret_cast<const float4*>(CDf);
        for (int u = tid; u < 20*24; u += 256) {
            int r = u / 24, c = u % 24;
            const float4* e4 = Ef4 + r*RS4;
            const float4* d4 = CD4 + (20+c)*RS4;
            float s = 0.0f;
            #pragma unroll
            for (int k4 = 0; k4 < RS4; ++k4) {
                float4 a = e4[k4], b = d4[k4];
                s += a.x*b.x + a.y*b.y + a.z*b.z + a.w*b.w;
            }
            ETf[r*26 + c] = 0.5f * (tanhf(0.1f * s) + 1.0f);
        }
    }
    __syncthreads();

    // ---- stencil derivatives + curvature penalty (fp32, fp64 accum) ----
    auto EXf = [&](int r, int k) -> float {
        int aab = a0 - 2 + r;
        if (aab == 0)      return (ETf[(r+1)*26+k] - ETf[r*26+k])     / g + SCADDF;
        if (aab == NP-1)   return (ETf[r*26+k]     - ETf[(r-1)*26+k]) / g + SCADDF;
        return (ETf[(r+1)*26+k] - ETf[(r-1)*26+k]) / (2.0f*g) + SCADDF;
    };
    auto EYf = [&](int r, int k) -> float {
        int bab = b0 - 2 + k;
        if (bab == 0)      return (ETf[r*26+k+1] - ETf[r*26+k])   / g + SCADDF;
        if (bab == NM-1)   return (ETf[r*26+k]   - ETf[r*26+k-1]) / g + SCADDF;
        return (ETf[r*26+k+1] - ETf[r*26+k-1]) / (2.0f*g) + SCADDF;
    };

    double local = 0.0;
    for (int u = tid; u < 16*20; u += 256) {        // 320 outputs, fixed order
        const int aa = u / 20, bb_ = u % 20;
        const int a = a0 + aa, b = b0 + bb_;
        if (a < NP) {                               // b < NM always
            const int ar = aa + 2, kc = bb_ + 2;
            const float exv = EXf(ar, kc);
            const float eyv = EYf(ar, kc);
            float exx, exy, eyy;
            if (a == 0)         exx = (EXf(ar+1,kc) - EXf(ar,kc))   / g;
            else if (a == NP-1) exx = (EXf(ar,kc)   - EXf(ar-1,kc)) / g;
            else                exx = (EXf(ar+1,kc) - EXf(ar-1,kc)) / (2.0f*g);
            if (b == 0)         exy = (EXf(ar,kc+1) - EXf(ar,kc))   / g;
            else if (b == NM-1) exy = (EXf(ar,kc)   - EXf(ar,kc-1)) / g;
            else                exy = (EXf(ar,kc+1) - EXf(ar,kc-1)) / (2.0f*g);
            if (b == 0)         eyy = (EYf(ar,kc+1) - EYf(ar,kc))   / g;
            else if (b == NM-1) eyy = (EYf(ar,kc)   - EYf(ar,kc-1)) / g;
            else                eyy = (EYf(ar,kc+1) - EYf(ar,kc-1)) / (2.0f*g);

            float epsv = sqrtf(exv*exv + eyv*eyv);
            const float epsv_min = 1.6666667e-33f;  // 1e-32/6
            if (epsv < epsv_min) epsv = epsv_min;
            const float kk = (exv*exv*eyy - 2.0f*exv*eyv*exy + eyv*eyv*exx)
                             / (epsv*epsv*epsv);
            const float cc = fabsf(kk * atanf(epsv / ETf[ar*26+kc])) - pi_d;
            float v = fmaxf(cc, 0.0f) * g * g;
            if (!isnan(v)) local += (double)v;
        }
    }

    // ---- per-wave shfl reduce (fixed tree) + single barrier ----
    #pragma unroll
    for (int off = 32; off > 0; off >>= 1)
        local += __shfl_down(local, off, 64);
    if (lane == 0) wsum[tid >> 6] = local;
    __syncthreads();
    if (tid == 0)
        (ws + OFF_PART)[blockIdx.x] = (wsum[0] + wsum[1]) + (wsum[2] + wsum[3]);
}

// ---------------- finalize: 1 wave, shfl-only deterministic sum -------------
__global__ __launch_bounds__(64) void finalize_kernel(
        const double* __restrict__ ws, float* __restrict__ out) {
    const double* part = ws + OFF_PART;
    const int t = threadIdx.x;                       // 64 threads
    double s = 0.0;
    for (int i = t; i < NBLK; i += 64) s += part[i]; // fixed order
    #pragma unroll
    for (int off = 32; off > 0; off >>= 1)
        s += __shfl_down(s, off, 64);
    if (t == 0) out[0] = (float)s;
}

extern "C" void kernel_launch(void* const* d_in, const int* in_sizes, int n_in,
                              void* d_out, int out_size, void* d_ws, size_t ws_size,
                              hipStream_t stream) {
    const float* params = (const float*)d_in[0];
    const float* x_rho  = (const float*)d_in[1];
    const float* y_rho  = (const float*)d_in[2];
    const float* x_phi  = (const float*)d_in[3];
    const float* y_phi  = (const float*)d_in[4];
    double* ws = (double*)d_ws;
    float* out = (float*)d_out;

    penalty_kernel<<<NBLK, 256, 0, stream>>>(
        params, x_rho, y_rho, x_phi, y_phi, ws);
    finalize_kernel<<<1, 64, 0, stream>>>(ws, out);
}